// Round 12
// baseline (316.877 us; speedup 1.0000x reference)
//
#include <hip/hip_runtime.h>
#include <hip/hip_bf16.h>
#include <math.h>

#define N_NODES 50000
#define N_EDGES 800000
#define ETOT (N_EDGES + N_NODES)   // 850000 with self loops
#define NGRP 196                   // ceil(50000/256) coarse dst groups
#define HBLK 416                   // hist/passA blocks: 416*2048 >= ETOT

typedef __attribute__((ext_vector_type(8))) short short8;      // 8 bf16 (4 VGPRs)
typedef __attribute__((ext_vector_type(4))) float floatx4;
typedef __attribute__((ext_vector_type(2))) float f32x2;       // -> v_pk_* f32 ops

// bf16 (raw u16 pairs) -> f32 decode: 1 VALU op each
__device__ __forceinline__ float bf_lo(unsigned u) { return __uint_as_float(u << 16); }
__device__ __forceinline__ float bf_hi(unsigned u) { return __uint_as_float(u & 0xffff0000u); }
// f32 -> bf16 raw bits, RNE
__device__ __forceinline__ unsigned short f2bf(float f) {
    unsigned u = __float_as_uint(f);
    return (unsigned short)((u + 0x7fffu + ((u >> 16) & 1u)) >> 16);
}
__device__ __forceinline__ unsigned pack2bf(float a, float b) {
    return (unsigned)f2bf(a) | ((unsigned)f2bf(b) << 16);
}
// butterfly add via DPP (VALU pipe, no LDS): ctrl must be a literal
#define DPP_ADD(p, ctrl) \
    (p) += __int_as_float(__builtin_amdgcn_update_dpp(0, __float_as_int(p), (ctrl), 0xF, 0xF, true))

// ==== K1: weight prep (bf16 transpose/concat) + coarse dst histogram ========
// Blocks [0,400): weight prep. Blocks [400, 400+HBLK): per-block LDS
// histogram of dst>>8 -> private 256-bin slab (part). No global atomics.
__global__ __launch_bounds__(256) void k_prep(const float* __restrict__ W1l,
                                              const float* __restrict__ W1r,
                                              const float* __restrict__ W2l,
                                              const float* __restrict__ W2r,
                                              const float* __restrict__ Wlin,
                                              unsigned short* __restrict__ Wt1,
                                              unsigned short* __restrict__ Wt2,
                                              unsigned short* __restrict__ Wt3,
                                              const int* __restrict__ ei,
                                              unsigned* __restrict__ part) {
    __shared__ unsigned sh[256];
    const int b = blockIdx.x;
    const int t = threadIdx.x;
    if (b < 400) {
        const int idx = b * 256 + t;
        if (idx < 65536) {
            const int k = idx >> 9;          // 0..127
            const int n = idx & 511;         // 0..511
            const float v = (n < 256) ? W1l[k * 256 + n] : W1r[k * 256 + (n - 256)];
            Wt1[n * 128 + k] = f2bf(v);
        } else if (idx < 98304) {
            const int j = idx - 65536;       // 0..32767
            const int k = j >> 7;            // 0..255
            const int n = j & 127;           // 0..127
            const float v = (n < 64) ? W2l[k * 64 + n] : W2r[k * 64 + (n - 64)];
            Wt2[n * 256 + k] = f2bf(v);
        } else {
            const int j = idx - 98304;       // 0..4095
            const int n = j >> 6, k = j & 63;
            Wt3[n * 64 + k] = f2bf(Wlin[k * 64 + n]);
        }
        return;
    }
    // coarse histogram path (per-block partial)
    const int bb = b - 400;
    sh[t] = 0;
    __syncthreads();
#pragma unroll
    for (int j = 0; j < 8; j++) {
        const int e = bb * 2048 + j * 256 + t;
        if (e < ETOT) {
            const int d = (e < N_EDGES) ? ei[N_EDGES + e] : (e - N_EDGES);
            atomicAdd(&sh[d >> 8], 1u);
        }
    }
    __syncthreads();
    part[bb * 256 + t] = sh[t];
}

// ==== K2: fused layer-1 MFMA projection (391 blocks, BOTH flavors) + passA ==
// Blocks [0,391): projection (x staged once, flavor loop).
// Blocks [391, 391+HBLK): CSR pass A. Each passA block SELF-DERIVES its
// cursors from part (coalesced sweep + wave-scan); bb==0 writes g_off.
// ZERO global atomics.
__global__ __launch_bounds__(256) void k_g1h(const float* __restrict__ x,
                                             const unsigned short* __restrict__ Wt1,
                                             unsigned short* __restrict__ xlb,
                                             unsigned short* __restrict__ xrb,
                                             const int* __restrict__ ei,
                                             const unsigned* __restrict__ part,
                                             int* __restrict__ g_off,
                                             unsigned* __restrict__ tmp) {
    __shared__ unsigned short sA[128 * 136];
    const int b = blockIdx.x;
    const int t = threadIdx.x;
    if (b >= 391) {   // CSR pass A (atomic-free vs global)
        __shared__ unsigned cur[256];
        __shared__ int wsum[4];
        const int bb = b - 391;
        const int lane = t & 63, wv = t >> 6;
        unsigned total_t = 0, base_t = 0;
        for (int b2 = 0; b2 < HBLK; b2++) {
            const unsigned v = part[b2 * 256 + t];
            total_t += v;
            base_t += (b2 < bb) ? v : 0u;
        }
        int incl = (int)total_t;
#pragma unroll
        for (int off = 1; off < 64; off <<= 1) {
            const int u = __shfl_up(incl, off);
            if (lane >= off) incl += u;
        }
        if (lane == 63) wsum[wv] = incl;
        __syncthreads();
        int woff = 0;
#pragma unroll
        for (int j = 0; j < 4; j++) woff += (j < wv) ? wsum[j] : 0;
        const int excl = incl - (int)total_t + woff;
        if (bb == 0) g_off[t] = excl;       // ready before k_bsort launches
        cur[t] = (unsigned)excl + base_t;
        __syncthreads();
#pragma unroll
        for (int j = 0; j < 8; j++) {
            const int e = bb * 2048 + j * 256 + t;
            if (e < ETOT) {
                int s, d;
                if (e < N_EDGES) { s = ei[e]; d = ei[N_EDGES + e]; }
                else { s = d = e - N_EDGES; }
                const unsigned item = ((unsigned)d << 16) | (unsigned)s;
                const unsigned pos = atomicAdd(&cur[d >> 8], 1u);   // LDS atomic
                tmp[pos] = item;
            }
        }
        return;
    }
    const int lane = t & 63, wv = t >> 6;
    const int m0 = b * 128;
#pragma unroll
    for (int j = 0; j < 16; j++) {
        const int i4 = t + j * 256;
        const int row = i4 >> 5, k4 = i4 & 31;
        float4 v = make_float4(0.f, 0.f, 0.f, 0.f);
        if (m0 + row < N_NODES) v = ((const float4*)x)[(long)(m0 + row) * 32 + k4];
        ushort4 u;
        u.x = f2bf(v.x); u.y = f2bf(v.y); u.z = f2bf(v.z); u.w = f2bf(v.w);
        *(ushort4*)&sA[row * 136 + k4 * 4] = u;
    }
    __syncthreads();
    const int l15 = lane & 15, quad = lane >> 4;
    const int nloc0 = wv * 64;
    for (int flavor = 0; flavor < 2; ++flavor) {
        unsigned short* outp = flavor ? xrb : xlb;
        short8 bfr[4][4];
#pragma unroll
        for (int nt = 0; nt < 4; nt++)
#pragma unroll
            for (int ks = 0; ks < 4; ks++)
                bfr[nt][ks] = *(const short8*)&Wt1[(flavor * 256 + nloc0 + nt * 16 + l15) * 128 + ks * 32 + quad * 8];
        for (int mt = 0; mt < 8; mt++) {
            short8 a[4];
#pragma unroll
            for (int ks = 0; ks < 4; ks++)
                a[ks] = *(const short8*)&sA[(mt * 16 + l15) * 136 + ks * 32 + quad * 8];
            floatx4 acc[4];
#pragma unroll
            for (int nt = 0; nt < 4; nt++) {
                acc[nt] = (floatx4)(0.f);
#pragma unroll
                for (int ks = 0; ks < 4; ks++)
                    acc[nt] = __builtin_amdgcn_mfma_f32_16x16x32_bf16(a[ks], bfr[nt][ks], acc[nt], 0, 0, 0);
            }
            const int mrow0 = m0 + mt * 16 + quad * 4;
#pragma unroll
            for (int nt = 0; nt < 4; nt++) {
                const int n = nloc0 + nt * 16 + l15;
#pragma unroll
                for (int r = 0; r < 4; r++) {
                    const int m = mrow0 + r;
                    if (m < N_NODES) outp[(long)m * 256 + n] = f2bf(acc[nt][r]);
                }
            }
        }
    }
}

// ==== K3: CSR pass B — per-group counting sort -> csr + rowstart + deg ======
__global__ __launch_bounds__(256) void k_bsort(const unsigned* __restrict__ tmp,
                                               const int* __restrict__ g_off,
                                               int* __restrict__ rowstart,
                                               int* __restrict__ deg,
                                               int* __restrict__ csr) {
    __shared__ unsigned h[256];
    __shared__ unsigned cur[256];
    __shared__ int wsum[4];
    const int t = threadIdx.x, lane = t & 63, wv = t >> 6;
    const int g = blockIdx.x;
    const int base = g_off[g];
    const int n = g_off[g + 1] - base;
    h[t] = 0;
    __syncthreads();
    for (int i = t; i < n; i += 256)
        atomicAdd(&h[(tmp[base + i] >> 16) & 255u], 1u);
    __syncthreads();
    const int v = (int)h[t];
    int incl = v;
#pragma unroll
    for (int off = 1; off < 64; off <<= 1) {
        const int u = __shfl_up(incl, off);
        if (lane >= off) incl += u;
    }
    if (lane == 63) wsum[wv] = incl;
    __syncthreads();
    int woff = 0;
#pragma unroll
    for (int j = 0; j < 4; j++) woff += (j < wv) ? wsum[j] : 0;
    const int excl = incl - v + woff;
    const int d = g * 256 + t;
    if (d < N_NODES) {
        rowstart[d] = base + excl;
        deg[d] = v;
    }
    cur[t] = (unsigned)excl;
    __syncthreads();
    for (int i = t; i < n; i += 256) {
        const unsigned item = tmp[base + i];
        const unsigned p = atomicAdd(&cur[(item >> 16) & 255u], 1u);
        csr[base + (int)p] = (int)((item & 0xFFFFu) << 9);   // byte off into 512B rows
    }
}

// ==== K4: layer-1 fused node kernel + LAYER-2 PROJECTION via MFMA ===========
// Gather/softmax as before (fabric-bound, ~200MB fill). Epilogue: the block's
// 4 h1 rows (bf16, in regs) -> zero-padded 16x264 LDS tile -> 16x16x32 MFMA
// against Wt2 (each wave: 32-col slice, K=256, unroll-2 keeps VGPR <= 64).
// Kills k_gemm2: H1b 25.6MB write + 25.6MB re-read + one launch GONE.
// __launch_bounds__(256,8) pins occupancy (VGPR cap 64) for the gather loop.
__global__ __launch_bounds__(256, 8) void k_node1(const int* __restrict__ rowstart,
                                                  const int* __restrict__ deg,
                                                  const int* __restrict__ csr,
                                                  const uint4* __restrict__ xlb,   // bf16 row = 32 uint4
                                                  const uint4* __restrict__ xrb,   // bf16 row = 32 uint4
                                                  const float* __restrict__ att,   // [256]
                                                  const float* __restrict__ b1,
                                                  const unsigned short* __restrict__ Wt2, // [128][256] n-major
                                                  unsigned short* __restrict__ xl2,  // [N,64] bf16
                                                  unsigned short* __restrict__ xr2) {// [N,64] bf16
    __shared__ unsigned short sH[16 * 264];  // rows 0-3 = block's h1 rows; 4-15 zero
    const int lane = threadIdx.x & 63;
    const int wv = threadIdx.x >> 6;
    const int node = blockIdx.x * 4 + wv;   // 50000 % 4 == 0
    const int g = lane >> 5;                // edge slot
    const int l = lane & 31;                // covers elems 8l..8l+7
    const char* xlbase = (const char*)xlb;
    const uint4 xru = xrb[(long)node * 32 + l];
    const float4 ta = ((const float4*)att)[2 * l];
    const float4 tb = ((const float4*)att)[2 * l + 1];
    f32x2 xp[4], tp[4];
    xp[0] = (f32x2){bf_lo(xru.x), bf_hi(xru.x)};
    xp[1] = (f32x2){bf_lo(xru.y), bf_hi(xru.y)};
    xp[2] = (f32x2){bf_lo(xru.z), bf_hi(xru.z)};
    xp[3] = (f32x2){bf_lo(xru.w), bf_hi(xru.w)};
    tp[0] = (f32x2){ta.x, ta.y}; tp[1] = (f32x2){ta.z, ta.w};
    tp[2] = (f32x2){tb.x, tb.y}; tp[3] = (f32x2){tb.z, tb.w};
    const int start = rowstart[node];
    const int cnt = deg[node];
    const int ns = (cnt - g + 1) >> 1;      // my slot's edge count
    float den = 0.f;
    f32x2 acc[4];
#pragma unroll
    for (int c = 0; c < 4; c++) acc[c] = (f32x2)(0.f);

    auto body = [&](const uint4& rr) {
        f32x2 a0, a1, a2, a3;
        a0.x = bf_lo(rr.x); a0.y = bf_hi(rr.x);
        a1.x = bf_lo(rr.y); a1.y = bf_hi(rr.y);
        a2.x = bf_lo(rr.z); a2.y = bf_hi(rr.z);
        a3.x = bf_lo(rr.w); a3.y = bf_hi(rr.w);
        f32x2 v = a0 + xp[0];
        f32x2 p2 = __builtin_elementwise_max(v, v * 0.2f) * tp[0];
        v = a1 + xp[1]; p2 += __builtin_elementwise_max(v, v * 0.2f) * tp[1];
        v = a2 + xp[2]; p2 += __builtin_elementwise_max(v, v * 0.2f) * tp[2];
        v = a3 + xp[3]; p2 += __builtin_elementwise_max(v, v * 0.2f) * tp[3];
        float p = p2.x + p2.y;
        DPP_ADD(p, 0xB1);    // xor1 (quad_perm [1,0,3,2])
        DPP_ADD(p, 0x4E);    // xor2 (quad_perm [2,3,0,1])
        DPP_ADD(p, 0x141);   // xor4 (row_half_mirror)
        const float w = __expf(p);
        acc[0] += a0 * w;
        acc[1] += a1 * w;
        acc[2] += a2 * w;
        acc[3] += a3 * w;
        den += w;
    };

    uint4 rcur = make_uint4(0, 0, 0, 0), rnext = rcur;
    if (ns > 0) rcur = *((const uint4*)(xlbase + csr[start + g]) + l);
    if (ns > 1) rnext = *((const uint4*)(xlbase + csr[start + 2 + g]) + l);
    int i = 0;
    for (; i + 2 < ns; i++) {               // steady state: unconditional prefetch
        const uint4 r2 = *((const uint4*)(xlbase + csr[start + 2 * (i + 2) + g]) + l);
        body(rcur);
        rcur = rnext; rnext = r2;
    }
    for (; i < ns; i++) {                   // epilogue (<=2 iterations)
        body(rcur);
        rcur = rnext;
    }
    // combine across the 2 slots (lane <-> lane^32 hold the same elems)
    den += __shfl_xor(den, 32);
    const float inv = 1.f / (den + 1e-16f);
#pragma unroll
    for (int c = 0; c < 4; c++) {
        f32x2 t2 = acc[c];
        t2.x += __shfl_xor(t2.x, 32);
        t2.y += __shfl_xor(t2.y, 32);
        acc[c] = t2;
    }
    const float4 ba = ((const float4*)b1)[2 * l];
    const float4 bb = ((const float4*)b1)[2 * l + 1];
    f32x2 bp[4];
    bp[0] = (f32x2){ba.x, ba.y}; bp[1] = (f32x2){ba.z, ba.w};
    bp[2] = (f32x2){bb.x, bb.y}; bp[3] = (f32x2){bb.z, bb.w};
    float o[8];
#pragma unroll
    for (int c = 0; c < 4; c++) {
        f32x2 t2 = acc[c] * inv + bp[c];
        o[2 * c]     = t2.x > 0.f ? t2.x : expm1f(t2.x);
        o[2 * c + 1] = t2.y > 0.f ? t2.y : expm1f(t2.y);
    }
    // ---- fused layer-2 projection (old k_gemm2, M=16 tile, rows 4-15 zero) ----
    if (g == 0) {   // lanes 0..31: wave wv writes its h1 row (bf16) to LDS row wv
        uint4 u;
        u.x = pack2bf(o[0], o[1]);
        u.y = pack2bf(o[2], o[3]);
        u.z = pack2bf(o[4], o[5]);
        u.w = pack2bf(o[6], o[7]);
        *(uint4*)&sH[wv * 264 + l * 8] = u;
    }
    {   // zero rows 4..15 (3168 shorts = 396 uint4, base 16B-aligned)
        uint4 z = make_uint4(0, 0, 0, 0);
        uint4* zp = (uint4*)&sH[4 * 264];
        for (int idx = threadIdx.x; idx < 396; idx += 256) zp[idx] = z;
    }
    __syncthreads();
    const int l15 = lane & 15, quad = lane >> 4;
    const int ncol0 = wv * 32;              // this wave's 32-col slice of [W2l|W2r]
    floatx4 c0 = (floatx4)(0.f), c1 = (floatx4)(0.f);
#pragma unroll 2
    for (int ks = 0; ks < 8; ks++) {
        const short8 a  = *(const short8*)&sH[l15 * 264 + ks * 32 + quad * 8];
        const short8 w0 = *(const short8*)&Wt2[(ncol0 + l15) * 256 + ks * 32 + quad * 8];
        const short8 w1 = *(const short8*)&Wt2[(ncol0 + 16 + l15) * 256 + ks * 32 + quad * 8];
        c0 = __builtin_amdgcn_mfma_f32_16x16x32_bf16(a, w0, c0, 0, 0, 0);
        c1 = __builtin_amdgcn_mfma_f32_16x16x32_bf16(a, w1, c1, 0, 0, 0);
    }
    if (quad == 0) {                        // C rows 0-3 = the block's 4 nodes
        const long node0 = (long)blockIdx.x * 4;
        const int n0 = ncol0 + l15;         // c0's output column
        const int n1 = ncol0 + 16 + l15;    // c1's output column
#pragma unroll
        for (int r = 0; r < 4; r++) {
            const long m = node0 + r;
            const unsigned short v0 = f2bf(c0[r]);
            const unsigned short v1 = f2bf(c1[r]);
            if (n0 < 64) xl2[m * 64 + n0] = v0; else xr2[m * 64 + (n0 - 64)] = v0;
            if (n1 < 64) xl2[m * 64 + n1] = v1; else xr2[m * 64 + (n1 - 64)] = v1;
        }
    }
}

// ==== K5: layer-2 fused node kernel + FINAL LINEAR via MFMA =================
// 4 edge-slots x 16 lanes, DPP reduce; epilogue: stage the block's 4 h2 rows
// (bf16) into a zero-padded 16x72 LDS tile, then each wave runs the SAME
// 2-MFMA fragment pattern as the old k_gemm3 for its 16-col slice.
__global__ __launch_bounds__(256) void k_node2(const int* __restrict__ rowstart,
                                               const int* __restrict__ deg,
                                               const int* __restrict__ csr,
                                               const uint2* __restrict__ xlb,   // bf16 row = 16 uint2
                                               const uint2* __restrict__ xrb,   // bf16 row = 16 uint2
                                               const float* __restrict__ att,
                                               const float* __restrict__ b2,
                                               const unsigned short* __restrict__ Wt3, // [64][64] n-major
                                               const float* __restrict__ blin,
                                               float* __restrict__ out) {      // [N,64] fp32
    __shared__ unsigned short sH[16 * 72];   // rows 0-3 = this block's nodes; 4-15 zero
    const int lane = threadIdx.x & 63;
    const int wv = threadIdx.x >> 6;
    const int node = blockIdx.x * 4 + wv;   // 50000 % 4 == 0
    const int g = lane >> 4;                // edge slot (0..3)
    const int l = lane & 15;                // covers elems 4l..4l+3
    const char* xlbase = (const char*)xlb;
    const uint2 xru = xrb[(long)node * 16 + l];
    const float4 at4 = ((const float4*)att)[l];
    f32x2 xp[2], tp[2];
    xp[0] = (f32x2){bf_lo(xru.x), bf_hi(xru.x)};
    xp[1] = (f32x2){bf_lo(xru.y), bf_hi(xru.y)};
    tp[0] = (f32x2){at4.x, at4.y}; tp[1] = (f32x2){at4.z, at4.w};
    const int start = rowstart[node];
    const int cnt = deg[node];
    const int ns = (cnt - g + 3) >> 2;      // my slot's edge count (edges 4i+g)
    float den = 0.f;
    f32x2 acc[2];
    acc[0] = (f32x2)(0.f); acc[1] = (f32x2)(0.f);

    auto body = [&](const uint2& rr) {
        f32x2 a0, a1;
        a0.x = bf_lo(rr.x); a0.y = bf_hi(rr.x);
        a1.x = bf_lo(rr.y); a1.y = bf_hi(rr.y);
        f32x2 v = a0 + xp[0];
        f32x2 p2 = __builtin_elementwise_max(v, v * 0.2f) * tp[0];
        v = a1 + xp[1]; p2 += __builtin_elementwise_max(v, v * 0.2f) * tp[1];
        float p = p2.x + p2.y;
        DPP_ADD(p, 0xB1);    // xor1
        DPP_ADD(p, 0x4E);    // xor2
        DPP_ADD(p, 0x141);   // xor4 (row_half_mirror)
        DPP_ADD(p, 0x140);   // xor8 (row_mirror)
        const float w = __expf(p);
        acc[0] += a0 * w;
        acc[1] += a1 * w;
        den += w;
    };

    uint2 rcur = make_uint2(0, 0), rnext = rcur;
    if (ns > 0) rcur = *((const uint2*)(xlbase + (csr[start + g] >> 2)) + l);
    if (ns > 1) rnext = *((const uint2*)(xlbase + (csr[start + 4 + g] >> 2)) + l);
    int i = 0;
    for (; i + 2 < ns; i++) {
        const uint2 r2 = *((const uint2*)(xlbase + (csr[start + 4 * (i + 2) + g] >> 2)) + l);
        body(rcur);
        rcur = rnext; rnext = r2;
    }
    for (; i < ns; i++) {
        body(rcur);
        rcur = rnext;
    }
    // combine across 4 slots (xor 16 then xor 32 align same elems)
    den += __shfl_xor(den, 16);
    den += __shfl_xor(den, 32);
    const float inv = 1.f / (den + 1e-16f);
    float t0 = acc[0].x, t1 = acc[0].y, t2 = acc[1].x, t3 = acc[1].y;
    t0 += __shfl_xor(t0, 16); t0 += __shfl_xor(t0, 32);
    t1 += __shfl_xor(t1, 16); t1 += __shfl_xor(t1, 32);
    t2 += __shfl_xor(t2, 16); t2 += __shfl_xor(t2, 32);
    t3 += __shfl_xor(t3, 16); t3 += __shfl_xor(t3, 32);
    const float4 b4 = ((const float4*)b2)[l];
    float4 h4;
    h4.x = t0 * inv + b4.x; h4.x = h4.x > 0.f ? h4.x : expm1f(h4.x);
    h4.y = t1 * inv + b4.y; h4.y = h4.y > 0.f ? h4.y : expm1f(h4.y);
    h4.z = t2 * inv + b4.z; h4.z = h4.z > 0.f ? h4.z : expm1f(h4.z);
    h4.w = t3 * inv + b4.w; h4.w = h4.w > 0.f ? h4.w : expm1f(h4.w);
    // ---- fused final linear (old k_gemm3, M=16 tile w/ rows 4-15 zero) ----
    for (int idx = threadIdx.x; idx < 16 * 72; idx += 256) sH[idx] = 0;
    __syncthreads();
    if (g == 0) {   // lane < 16, l == lane; wave wv owns LDS row wv
        *(uint2*)&sH[wv * 72 + 4 * l] =
            make_uint2(pack2bf(h4.x, h4.y), pack2bf(h4.z, h4.w));
    }
    __syncthreads();
    const int l15 = lane & 15, quad = lane >> 4;
    const int n0 = wv * 16;                 // this wave's 16-col output slice
    const short8 a0  = *(const short8*)&sH[l15 * 72 + quad * 8];
    const short8 a1  = *(const short8*)&sH[l15 * 72 + 32 + quad * 8];
    const short8 bb0 = *(const short8*)&Wt3[(n0 + l15) * 64 + quad * 8];
    const short8 bb1 = *(const short8*)&Wt3[(n0 + l15) * 64 + 32 + quad * 8];
    floatx4 acc2 = (floatx4)(0.f);
    acc2 = __builtin_amdgcn_mfma_f32_16x16x32_bf16(a0, bb0, acc2, 0, 0, 0);
    acc2 = __builtin_amdgcn_mfma_f32_16x16x32_bf16(a1, bb1, acc2, 0, 0, 0);
    if (quad == 0) {                        // C rows 0-3 = the block's 4 nodes
        const float bl = blin[n0 + l15];
        const long node0 = (long)blockIdx.x * 4;
#pragma unroll
        for (int r = 0; r < 4; r++)
            out[(node0 + r) * 64 + n0 + l15] = acc2[r] + bl;
    }
}

extern "C" void kernel_launch(void* const* d_in, const int* in_sizes, int n_in,
                              void* d_out, int out_size, void* d_ws, size_t ws_size,
                              hipStream_t stream) {
    (void)in_sizes; (void)n_in; (void)out_size; (void)ws_size;
    const float* x    = (const float*)d_in[0];
    const int*   ei   = (const int*)d_in[1];
    const float* W1l  = (const float*)d_in[2];
    const float* W1r  = (const float*)d_in[3];
    const float* att1 = (const float*)d_in[4];
    const float* b1   = (const float*)d_in[5];
    const float* W2l  = (const float*)d_in[6];
    const float* W2r  = (const float*)d_in[7];
    const float* att2 = (const float*)d_in[8];
    const float* b2   = (const float*)d_in[9];
    const float* Wlin = (const float*)d_in[10];
    const float* blin = (const float*)d_in[11];

    float* ws = (float*)d_ws;
    unsigned short* XL1b = (unsigned short*)(ws);              // [N,256] bf16
    unsigned short* XR1b = (unsigned short*)(ws + 6400000);    // [N,256] bf16
    // CSR-build scratch (region formerly H1b; all dead before node1 runs):
    unsigned*       tmp  = (unsigned*)(ws + 12800000);         // 850K packed items
    unsigned*       part = (unsigned*)(ws + 14000000);         // 416*256 partial hist
    unsigned short* XL2b = (unsigned short*)(ws + 19200000);   // [N,64] bf16
    unsigned short* XR2b = (unsigned short*)(ws + 20800000);   // [N,64] bf16
    int* deg       = (int*)(ws + 22400000);        // 50,000
    int* rowstart  = (int*)(ws + 22450000);        // 50,000
    int* csr       = (int*)(ws + 22550000);        // 850,000 -> ends 23,400,000
    int* g_off     = (int*)(ws + 23430000);        // 256 (g_off[196] valid)
    unsigned short* Wt1 = (unsigned short*)(ws + 23500000);    // 65,536 shorts
    unsigned short* Wt2 = (unsigned short*)(ws + 23550000);    // 32,768 shorts
    unsigned short* Wt3 = (unsigned short*)(ws + 23600000);    // 4,096 shorts

    // K1: weight prep (400 blocks) + per-block coarse dst histograms (416 blocks)
    k_prep<<<400 + HBLK, 256, 0, stream>>>(W1l, W1r, W2l, W2r, Wlin,
                                           Wt1, Wt2, Wt3, ei, part);
    // K2: gemm1 both flavors (391 blocks) + self-deriving CSR pass A (416 blocks)
    k_g1h<<<391 + HBLK, 256, 0, stream>>>(x, Wt1, XL1b, XR1b, ei, part, g_off, tmp);
    // K3: CSR pass B: per-group counting sort -> csr/rowstart/deg
    k_bsort<<<NGRP, 256, 0, stream>>>(tmp, g_off, rowstart, deg, csr);
    // K4: layer-1 fused attention + layer-2 projection (gemm2 fused via MFMA)
    k_node1<<<12500, 256, 0, stream>>>(rowstart, deg, csr,
                                       (const uint4*)XL1b, (const uint4*)XR1b,
                                       att1, b1, Wt2, XL2b, XR2b);
    // K5: layer-2 fused attention + final linear (gemm3 fused via MFMA)
    k_node2<<<12500, 256, 0, stream>>>(rowstart, deg, csr,
                                       (const uint2*)XL2b, (const uint2*)XR2b,
                                       att2, b2, Wt3, blin, (float*)d_out);
}

// Round 13
// 274.906 us; speedup vs baseline: 1.1527x; 1.1527x over previous
//
#include <hip/hip_runtime.h>
#include <hip/hip_bf16.h>
#include <math.h>

#define N_NODES 50000
#define N_EDGES 800000
#define ETOT (N_EDGES + N_NODES)   // 850000 with self loops
#define NGRP 196                   // ceil(50000/256) coarse dst groups
#define HBLK 416                   // hist/passA blocks: 416*2048 >= ETOT

typedef __attribute__((ext_vector_type(8))) short short8;      // 8 bf16 (4 VGPRs)
typedef __attribute__((ext_vector_type(4))) float floatx4;
typedef __attribute__((ext_vector_type(2))) float f32x2;       // -> v_pk_* f32 ops

// bf16 (raw u16 pairs) -> f32 decode: 1 VALU op each
__device__ __forceinline__ float bf_lo(unsigned u) { return __uint_as_float(u << 16); }
__device__ __forceinline__ float bf_hi(unsigned u) { return __uint_as_float(u & 0xffff0000u); }
// f32 -> bf16 raw bits, RNE
__device__ __forceinline__ unsigned short f2bf(float f) {
    unsigned u = __float_as_uint(f);
    return (unsigned short)((u + 0x7fffu + ((u >> 16) & 1u)) >> 16);
}
__device__ __forceinline__ unsigned pack2bf(float a, float b) {
    return (unsigned)f2bf(a) | ((unsigned)f2bf(b) << 16);
}
// butterfly add via DPP (VALU pipe, no LDS): ctrl must be a literal
#define DPP_ADD(p, ctrl) \
    (p) += __int_as_float(__builtin_amdgcn_update_dpp(0, __float_as_int(p), (ctrl), 0xF, 0xF, true))

// ==== K1: weight prep (bf16 transpose/concat) + coarse dst histogram ========
// Blocks [0,400): weight prep. Blocks [400, 400+HBLK): per-block LDS
// histogram of dst>>8 -> private 256-bin slab (part). No global atomics.
__global__ __launch_bounds__(256) void k_prep(const float* __restrict__ W1l,
                                              const float* __restrict__ W1r,
                                              const float* __restrict__ W2l,
                                              const float* __restrict__ W2r,
                                              const float* __restrict__ Wlin,
                                              unsigned short* __restrict__ Wt1,
                                              unsigned short* __restrict__ Wt2,
                                              unsigned short* __restrict__ Wt3,
                                              const int* __restrict__ ei,
                                              unsigned* __restrict__ part) {
    __shared__ unsigned sh[256];
    const int b = blockIdx.x;
    const int t = threadIdx.x;
    if (b < 400) {
        const int idx = b * 256 + t;
        if (idx < 65536) {
            const int k = idx >> 9;          // 0..127
            const int n = idx & 511;         // 0..511
            const float v = (n < 256) ? W1l[k * 256 + n] : W1r[k * 256 + (n - 256)];
            Wt1[n * 128 + k] = f2bf(v);
        } else if (idx < 98304) {
            const int j = idx - 65536;       // 0..32767
            const int k = j >> 7;            // 0..255
            const int n = j & 127;           // 0..127
            const float v = (n < 64) ? W2l[k * 64 + n] : W2r[k * 64 + (n - 64)];
            Wt2[n * 256 + k] = f2bf(v);
        } else {
            const int j = idx - 98304;       // 0..4095
            const int n = j >> 6, k = j & 63;
            Wt3[n * 64 + k] = f2bf(Wlin[k * 64 + n]);
        }
        return;
    }
    // coarse histogram path (per-block partial)
    const int bb = b - 400;
    sh[t] = 0;
    __syncthreads();
#pragma unroll
    for (int j = 0; j < 8; j++) {
        const int e = bb * 2048 + j * 256 + t;
        if (e < ETOT) {
            const int d = (e < N_EDGES) ? ei[N_EDGES + e] : (e - N_EDGES);
            atomicAdd(&sh[d >> 8], 1u);
        }
    }
    __syncthreads();
    part[bb * 256 + t] = sh[t];
}

// ==== K2: fused layer-1 MFMA projection (391 blocks, BOTH flavors) + passA ==
// Blocks [0,391): projection (x staged once, flavor loop).
// Blocks [391, 391+HBLK): CSR pass A. Each passA block SELF-DERIVES its
// cursors from part (coalesced sweep + wave-scan); bb==0 writes g_off.
// ZERO global atomics.
__global__ __launch_bounds__(256) void k_g1h(const float* __restrict__ x,
                                             const unsigned short* __restrict__ Wt1,
                                             unsigned short* __restrict__ xlb,
                                             unsigned short* __restrict__ xrb,
                                             const int* __restrict__ ei,
                                             const unsigned* __restrict__ part,
                                             int* __restrict__ g_off,
                                             unsigned* __restrict__ tmp) {
    __shared__ unsigned short sA[128 * 136];
    const int b = blockIdx.x;
    const int t = threadIdx.x;
    if (b >= 391) {   // CSR pass A (atomic-free vs global)
        __shared__ unsigned cur[256];
        __shared__ int wsum[4];
        const int bb = b - 391;
        const int lane = t & 63, wv = t >> 6;
        unsigned total_t = 0, base_t = 0;
        for (int b2 = 0; b2 < HBLK; b2++) {
            const unsigned v = part[b2 * 256 + t];
            total_t += v;
            base_t += (b2 < bb) ? v : 0u;
        }
        int incl = (int)total_t;
#pragma unroll
        for (int off = 1; off < 64; off <<= 1) {
            const int u = __shfl_up(incl, off);
            if (lane >= off) incl += u;
        }
        if (lane == 63) wsum[wv] = incl;
        __syncthreads();
        int woff = 0;
#pragma unroll
        for (int j = 0; j < 4; j++) woff += (j < wv) ? wsum[j] : 0;
        const int excl = incl - (int)total_t + woff;
        if (bb == 0) g_off[t] = excl;       // ready before k_bsort launches
        cur[t] = (unsigned)excl + base_t;
        __syncthreads();
#pragma unroll
        for (int j = 0; j < 8; j++) {
            const int e = bb * 2048 + j * 256 + t;
            if (e < ETOT) {
                int s, d;
                if (e < N_EDGES) { s = ei[e]; d = ei[N_EDGES + e]; }
                else { s = d = e - N_EDGES; }
                const unsigned item = ((unsigned)d << 16) | (unsigned)s;
                const unsigned pos = atomicAdd(&cur[d >> 8], 1u);   // LDS atomic
                tmp[pos] = item;
            }
        }
        return;
    }
    const int lane = t & 63, wv = t >> 6;
    const int m0 = b * 128;
#pragma unroll
    for (int j = 0; j < 16; j++) {
        const int i4 = t + j * 256;
        const int row = i4 >> 5, k4 = i4 & 31;
        float4 v = make_float4(0.f, 0.f, 0.f, 0.f);
        if (m0 + row < N_NODES) v = ((const float4*)x)[(long)(m0 + row) * 32 + k4];
        ushort4 u;
        u.x = f2bf(v.x); u.y = f2bf(v.y); u.z = f2bf(v.z); u.w = f2bf(v.w);
        *(ushort4*)&sA[row * 136 + k4 * 4] = u;
    }
    __syncthreads();
    const int l15 = lane & 15, quad = lane >> 4;
    const int nloc0 = wv * 64;
    for (int flavor = 0; flavor < 2; ++flavor) {
        unsigned short* outp = flavor ? xrb : xlb;
        short8 bfr[4][4];
#pragma unroll
        for (int nt = 0; nt < 4; nt++)
#pragma unroll
            for (int ks = 0; ks < 4; ks++)
                bfr[nt][ks] = *(const short8*)&Wt1[(flavor * 256 + nloc0 + nt * 16 + l15) * 128 + ks * 32 + quad * 8];
        for (int mt = 0; mt < 8; mt++) {
            short8 a[4];
#pragma unroll
            for (int ks = 0; ks < 4; ks++)
                a[ks] = *(const short8*)&sA[(mt * 16 + l15) * 136 + ks * 32 + quad * 8];
            floatx4 acc[4];
#pragma unroll
            for (int nt = 0; nt < 4; nt++) {
                acc[nt] = (floatx4)(0.f);
#pragma unroll
                for (int ks = 0; ks < 4; ks++)
                    acc[nt] = __builtin_amdgcn_mfma_f32_16x16x32_bf16(a[ks], bfr[nt][ks], acc[nt], 0, 0, 0);
            }
            const int mrow0 = m0 + mt * 16 + quad * 4;
#pragma unroll
            for (int nt = 0; nt < 4; nt++) {
                const int n = nloc0 + nt * 16 + l15;
#pragma unroll
                for (int r = 0; r < 4; r++) {
                    const int m = mrow0 + r;
                    if (m < N_NODES) outp[(long)m * 256 + n] = f2bf(acc[nt][r]);
                }
            }
        }
    }
}

// ==== K3: CSR pass B — per-group counting sort -> csr + rowstart + deg ======
__global__ __launch_bounds__(256) void k_bsort(const unsigned* __restrict__ tmp,
                                               const int* __restrict__ g_off,
                                               int* __restrict__ rowstart,
                                               int* __restrict__ deg,
                                               int* __restrict__ csr) {
    __shared__ unsigned h[256];
    __shared__ unsigned cur[256];
    __shared__ int wsum[4];
    const int t = threadIdx.x, lane = t & 63, wv = t >> 6;
    const int g = blockIdx.x;
    const int base = g_off[g];
    const int n = g_off[g + 1] - base;
    h[t] = 0;
    __syncthreads();
    for (int i = t; i < n; i += 256)
        atomicAdd(&h[(tmp[base + i] >> 16) & 255u], 1u);
    __syncthreads();
    const int v = (int)h[t];
    int incl = v;
#pragma unroll
    for (int off = 1; off < 64; off <<= 1) {
        const int u = __shfl_up(incl, off);
        if (lane >= off) incl += u;
    }
    if (lane == 63) wsum[wv] = incl;
    __syncthreads();
    int woff = 0;
#pragma unroll
    for (int j = 0; j < 4; j++) woff += (j < wv) ? wsum[j] : 0;
    const int excl = incl - v + woff;
    const int d = g * 256 + t;
    if (d < N_NODES) {
        rowstart[d] = base + excl;
        deg[d] = v;
    }
    cur[t] = (unsigned)excl;
    __syncthreads();
    for (int i = t; i < n; i += 256) {
        const unsigned item = tmp[base + i];
        const unsigned p = atomicAdd(&cur[(item >> 16) & 255u], 1u);
        csr[base + (int)p] = (int)((item & 0xFFFFu) << 9);   // byte off into 512B rows
    }
}

// ==== K4: layer-1 fused node kernel: 2 edge-slots x 32 lanes, DPP reduce ====
// At the fabric floor (~200MB compulsory per-XCD fill @ ~3.2 TB/s).
__global__ __launch_bounds__(256) void k_node1(const int* __restrict__ rowstart,
                                               const int* __restrict__ deg,
                                               const int* __restrict__ csr,
                                               const uint4* __restrict__ xlb,   // bf16 row = 32 uint4
                                               const uint4* __restrict__ xrb,   // bf16 row = 32 uint4
                                               const float* __restrict__ att,   // [256]
                                               const float* __restrict__ b1,
                                               uint4* __restrict__ h1b) {      // bf16 row = 32 uint4
    const int lane = threadIdx.x & 63;
    const int wv = threadIdx.x >> 6;
    const int node = blockIdx.x * 4 + wv;   // 50000 % 4 == 0
    const int g = lane >> 5;                // edge slot
    const int l = lane & 31;                // covers elems 8l..8l+7
    const char* xlbase = (const char*)xlb;
    const uint4 xru = xrb[(long)node * 32 + l];
    const float4 ta = ((const float4*)att)[2 * l];
    const float4 tb = ((const float4*)att)[2 * l + 1];
    f32x2 xp[4], tp[4];
    xp[0] = (f32x2){bf_lo(xru.x), bf_hi(xru.x)};
    xp[1] = (f32x2){bf_lo(xru.y), bf_hi(xru.y)};
    xp[2] = (f32x2){bf_lo(xru.z), bf_hi(xru.z)};
    xp[3] = (f32x2){bf_lo(xru.w), bf_hi(xru.w)};
    tp[0] = (f32x2){ta.x, ta.y}; tp[1] = (f32x2){ta.z, ta.w};
    tp[2] = (f32x2){tb.x, tb.y}; tp[3] = (f32x2){tb.z, tb.w};
    const int start = rowstart[node];
    const int cnt = deg[node];
    const int ns = (cnt - g + 1) >> 1;      // my slot's edge count
    float den = 0.f;
    f32x2 acc[4];
#pragma unroll
    for (int c = 0; c < 4; c++) acc[c] = (f32x2)(0.f);

    auto body = [&](const uint4& rr) {
        f32x2 a0, a1, a2, a3;
        a0.x = bf_lo(rr.x); a0.y = bf_hi(rr.x);
        a1.x = bf_lo(rr.y); a1.y = bf_hi(rr.y);
        a2.x = bf_lo(rr.z); a2.y = bf_hi(rr.z);
        a3.x = bf_lo(rr.w); a3.y = bf_hi(rr.w);
        f32x2 v = a0 + xp[0];
        f32x2 p2 = __builtin_elementwise_max(v, v * 0.2f) * tp[0];
        v = a1 + xp[1]; p2 += __builtin_elementwise_max(v, v * 0.2f) * tp[1];
        v = a2 + xp[2]; p2 += __builtin_elementwise_max(v, v * 0.2f) * tp[2];
        v = a3 + xp[3]; p2 += __builtin_elementwise_max(v, v * 0.2f) * tp[3];
        float p = p2.x + p2.y;
        DPP_ADD(p, 0xB1);    // xor1 (quad_perm [1,0,3,2])
        DPP_ADD(p, 0x4E);    // xor2 (quad_perm [2,3,0,1])
        DPP_ADD(p, 0x141);   // xor4 (row_half_mirror)
        const float w = __expf(p);
        acc[0] += a0 * w;
        acc[1] += a1 * w;
        acc[2] += a2 * w;
        acc[3] += a3 * w;
        den += w;
    };

    uint4 rcur = make_uint4(0, 0, 0, 0), rnext = rcur;
    if (ns > 0) rcur = *((const uint4*)(xlbase + csr[start + g]) + l);
    if (ns > 1) rnext = *((const uint4*)(xlbase + csr[start + 2 + g]) + l);
    int i = 0;
    for (; i + 2 < ns; i++) {               // steady state: unconditional prefetch
        const uint4 r2 = *((const uint4*)(xlbase + csr[start + 2 * (i + 2) + g]) + l);
        body(rcur);
        rcur = rnext; rnext = r2;
    }
    for (; i < ns; i++) {                   // epilogue (<=2 iterations)
        body(rcur);
        rcur = rnext;
    }
    // combine across the 2 slots (lane <-> lane^32 hold the same elems)
    den += __shfl_xor(den, 32);
    const float inv = 1.f / (den + 1e-16f);
#pragma unroll
    for (int c = 0; c < 4; c++) {
        f32x2 t2 = acc[c];
        t2.x += __shfl_xor(t2.x, 32);
        t2.y += __shfl_xor(t2.y, 32);
        acc[c] = t2;
    }
    const float4 ba = ((const float4*)b1)[2 * l];
    const float4 bb = ((const float4*)b1)[2 * l + 1];
    f32x2 bp[4];
    bp[0] = (f32x2){ba.x, ba.y}; bp[1] = (f32x2){ba.z, ba.w};
    bp[2] = (f32x2){bb.x, bb.y}; bp[3] = (f32x2){bb.z, bb.w};
    float o[8];
#pragma unroll
    for (int c = 0; c < 4; c++) {
        f32x2 t2 = acc[c] * inv + bp[c];
        o[2 * c]     = t2.x > 0.f ? t2.x : expm1f(t2.x);
        o[2 * c + 1] = t2.y > 0.f ? t2.y : expm1f(t2.y);
    }
    if (g == 0) {
        uint4 u;
        u.x = pack2bf(o[0], o[1]);
        u.y = pack2bf(o[2], o[3]);
        u.z = pack2bf(o[4], o[5]);
        u.w = pack2bf(o[6], o[7]);
        h1b[(long)node * 32 + l] = u;
    }
}

// ==== K5: layer-2 MFMA projection: h1(bf16)[N,256] @ [W2l|W2r] ==============
__global__ __launch_bounds__(256) void k_gemm2(const uint4* __restrict__ h,   // bf16 rows
                                               const unsigned short* __restrict__ Wt2,
                                               unsigned short* __restrict__ xlb,
                                               unsigned short* __restrict__ xrb) {
    __shared__ unsigned short sA[64 * 264];
    const int t = threadIdx.x;
    const int lane = t & 63, wv = t >> 6;
    const int m0 = blockIdx.x * 64;
#pragma unroll
    for (int j = 0; j < 8; j++) {
        const int i8 = t + j * 256;          // 0..2047, 8 shorts each
        const int row = i8 >> 5, c8 = i8 & 31;
        uint4 v = make_uint4(0, 0, 0, 0);
        if (m0 + row < N_NODES) v = h[(long)(m0 + row) * 32 + c8];
        *(uint4*)&sA[row * 264 + c8 * 8] = v;
    }
    __syncthreads();
    const int l15 = lane & 15, quad = lane >> 4;
    const int ncol0 = wv * 32;
    short8 b[2][8];
#pragma unroll
    for (int nt = 0; nt < 2; nt++)
#pragma unroll
        for (int ks = 0; ks < 8; ks++)
            b[nt][ks] = *(const short8*)&Wt2[(ncol0 + nt * 16 + l15) * 256 + ks * 32 + quad * 8];
    for (int mt = 0; mt < 4; mt++) {
        floatx4 acc[2];
        acc[0] = (floatx4)(0.f);
        acc[1] = (floatx4)(0.f);
#pragma unroll
        for (int ks = 0; ks < 8; ks++) {
            const short8 a = *(const short8*)&sA[(mt * 16 + l15) * 264 + ks * 32 + quad * 8];
            acc[0] = __builtin_amdgcn_mfma_f32_16x16x32_bf16(a, b[0][ks], acc[0], 0, 0, 0);
            acc[1] = __builtin_amdgcn_mfma_f32_16x16x32_bf16(a, b[1][ks], acc[1], 0, 0, 0);
        }
        const int mrow0 = m0 + mt * 16 + quad * 4;
#pragma unroll
        for (int nt = 0; nt < 2; nt++) {
            const int n = ncol0 + nt * 16 + l15;
#pragma unroll
            for (int r = 0; r < 4; r++) {
                const int m = mrow0 + r;
                if (m < N_NODES) {
                    if (n < 64) xlb[(long)m * 64 + n] = f2bf(acc[nt][r]);
                    else        xrb[(long)m * 64 + (n - 64)] = f2bf(acc[nt][r]);
                }
            }
        }
    }
}

// ==== K6: layer-2 fused node kernel + FINAL LINEAR via MFMA =================
// 4 edge-slots x 16 lanes, DPP reduce; epilogue: stage the block's 4 h2 rows
// (bf16) into a zero-padded 16x72 LDS tile, then each wave runs the SAME
// 2-MFMA fragment pattern as the old k_gemm3 for its 16-col slice.
// (Wt3 is 8KB -> per-block re-read is ~100MB aggregate: absorbable. Wt2's
// 64KB was NOT -> round-12's gemm2-fusion regressed 2x and was reverted.)
__global__ __launch_bounds__(256) void k_node2(const int* __restrict__ rowstart,
                                               const int* __restrict__ deg,
                                               const int* __restrict__ csr,
                                               const uint2* __restrict__ xlb,   // bf16 row = 16 uint2
                                               const uint2* __restrict__ xrb,   // bf16 row = 16 uint2
                                               const float* __restrict__ att,
                                               const float* __restrict__ b2,
                                               const unsigned short* __restrict__ Wt3, // [64][64] n-major
                                               const float* __restrict__ blin,
                                               float* __restrict__ out) {      // [N,64] fp32
    __shared__ unsigned short sH[16 * 72];   // rows 0-3 = this block's nodes; 4-15 zero
    const int lane = threadIdx.x & 63;
    const int wv = threadIdx.x >> 6;
    const int node = blockIdx.x * 4 + wv;   // 50000 % 4 == 0
    const int g = lane >> 4;                // edge slot (0..3)
    const int l = lane & 15;                // covers elems 4l..4l+3
    const char* xlbase = (const char*)xlb;
    const uint2 xru = xrb[(long)node * 16 + l];
    const float4 at4 = ((const float4*)att)[l];
    f32x2 xp[2], tp[2];
    xp[0] = (f32x2){bf_lo(xru.x), bf_hi(xru.x)};
    xp[1] = (f32x2){bf_lo(xru.y), bf_hi(xru.y)};
    tp[0] = (f32x2){at4.x, at4.y}; tp[1] = (f32x2){at4.z, at4.w};
    const int start = rowstart[node];
    const int cnt = deg[node];
    const int ns = (cnt - g + 3) >> 2;      // my slot's edge count (edges 4i+g)
    float den = 0.f;
    f32x2 acc[2];
    acc[0] = (f32x2)(0.f); acc[1] = (f32x2)(0.f);

    auto body = [&](const uint2& rr) {
        f32x2 a0, a1;
        a0.x = bf_lo(rr.x); a0.y = bf_hi(rr.x);
        a1.x = bf_lo(rr.y); a1.y = bf_hi(rr.y);
        f32x2 v = a0 + xp[0];
        f32x2 p2 = __builtin_elementwise_max(v, v * 0.2f) * tp[0];
        v = a1 + xp[1]; p2 += __builtin_elementwise_max(v, v * 0.2f) * tp[1];
        float p = p2.x + p2.y;
        DPP_ADD(p, 0xB1);    // xor1
        DPP_ADD(p, 0x4E);    // xor2
        DPP_ADD(p, 0x141);   // xor4 (row_half_mirror)
        DPP_ADD(p, 0x140);   // xor8 (row_mirror)
        const float w = __expf(p);
        acc[0] += a0 * w;
        acc[1] += a1 * w;
        den += w;
    };

    uint2 rcur = make_uint2(0, 0), rnext = rcur;
    if (ns > 0) rcur = *((const uint2*)(xlbase + (csr[start + g] >> 2)) + l);
    if (ns > 1) rnext = *((const uint2*)(xlbase + (csr[start + 4 + g] >> 2)) + l);
    int i = 0;
    for (; i + 2 < ns; i++) {
        const uint2 r2 = *((const uint2*)(xlbase + (csr[start + 4 * (i + 2) + g] >> 2)) + l);
        body(rcur);
        rcur = rnext; rnext = r2;
    }
    for (; i < ns; i++) {
        body(rcur);
        rcur = rnext;
    }
    // combine across 4 slots (xor 16 then xor 32 align same elems)
    den += __shfl_xor(den, 16);
    den += __shfl_xor(den, 32);
    const float inv = 1.f / (den + 1e-16f);
    float t0 = acc[0].x, t1 = acc[0].y, t2 = acc[1].x, t3 = acc[1].y;
    t0 += __shfl_xor(t0, 16); t0 += __shfl_xor(t0, 32);
    t1 += __shfl_xor(t1, 16); t1 += __shfl_xor(t1, 32);
    t2 += __shfl_xor(t2, 16); t2 += __shfl_xor(t2, 32);
    t3 += __shfl_xor(t3, 16); t3 += __shfl_xor(t3, 32);
    const float4 b4 = ((const float4*)b2)[l];
    float4 h4;
    h4.x = t0 * inv + b4.x; h4.x = h4.x > 0.f ? h4.x : expm1f(h4.x);
    h4.y = t1 * inv + b4.y; h4.y = h4.y > 0.f ? h4.y : expm1f(h4.y);
    h4.z = t2 * inv + b4.z; h4.z = h4.z > 0.f ? h4.z : expm1f(h4.z);
    h4.w = t3 * inv + b4.w; h4.w = h4.w > 0.f ? h4.w : expm1f(h4.w);
    // ---- fused final linear (old k_gemm3, M=16 tile w/ rows 4-15 zero) ----
    for (int idx = threadIdx.x; idx < 16 * 72; idx += 256) sH[idx] = 0;
    __syncthreads();
    if (g == 0) {   // lane < 16, l == lane; wave wv owns LDS row wv
        *(uint2*)&sH[wv * 72 + 4 * l] =
            make_uint2(pack2bf(h4.x, h4.y), pack2bf(h4.z, h4.w));
    }
    __syncthreads();
    const int l15 = lane & 15, quad = lane >> 4;
    const int n0 = wv * 16;                 // this wave's 16-col output slice
    const short8 a0  = *(const short8*)&sH[l15 * 72 + quad * 8];
    const short8 a1  = *(const short8*)&sH[l15 * 72 + 32 + quad * 8];
    const short8 bb0 = *(const short8*)&Wt3[(n0 + l15) * 64 + quad * 8];
    const short8 bb1 = *(const short8*)&Wt3[(n0 + l15) * 64 + 32 + quad * 8];
    floatx4 acc2 = (floatx4)(0.f);
    acc2 = __builtin_amdgcn_mfma_f32_16x16x32_bf16(a0, bb0, acc2, 0, 0, 0);
    acc2 = __builtin_amdgcn_mfma_f32_16x16x32_bf16(a1, bb1, acc2, 0, 0, 0);
    if (quad == 0) {                        // C rows 0-3 = the block's 4 nodes
        const float bl = blin[n0 + l15];
        const long node0 = (long)blockIdx.x * 4;
#pragma unroll
        for (int r = 0; r < 4; r++)
            out[(node0 + r) * 64 + n0 + l15] = acc2[r] + bl;
    }
}

extern "C" void kernel_launch(void* const* d_in, const int* in_sizes, int n_in,
                              void* d_out, int out_size, void* d_ws, size_t ws_size,
                              hipStream_t stream) {
    (void)in_sizes; (void)n_in; (void)out_size; (void)ws_size;
    const float* x    = (const float*)d_in[0];
    const int*   ei   = (const int*)d_in[1];
    const float* W1l  = (const float*)d_in[2];
    const float* W1r  = (const float*)d_in[3];
    const float* att1 = (const float*)d_in[4];
    const float* b1   = (const float*)d_in[5];
    const float* W2l  = (const float*)d_in[6];
    const float* W2r  = (const float*)d_in[7];
    const float* att2 = (const float*)d_in[8];
    const float* b2   = (const float*)d_in[9];
    const float* Wlin = (const float*)d_in[10];
    const float* blin = (const float*)d_in[11];

    float* ws = (float*)d_ws;
    unsigned short* XL1b = (unsigned short*)(ws);              // [N,256] bf16
    unsigned short* XR1b = (unsigned short*)(ws + 6400000);    // [N,256] bf16
    uint4*          H1b  = (uint4*)(ws + 12800000);            // [N,256] bf16 (6.4M floats)
    // CSR-build scratch overlays H1b's region (all dead before node1 writes H1b):
    unsigned*       tmp  = (unsigned*)(ws + 12800000);         // 850K packed items
    unsigned*       part = (unsigned*)(ws + 14000000);         // 416*256 partial hist
    unsigned short* XL2b = (unsigned short*)(ws + 19200000);   // [N,64] bf16
    unsigned short* XR2b = (unsigned short*)(ws + 20800000);   // [N,64] bf16
    int* deg       = (int*)(ws + 22400000);        // 50,000
    int* rowstart  = (int*)(ws + 22450000);        // 50,000
    int* csr       = (int*)(ws + 22550000);        // 850,000 -> ends 23,400,000
    int* g_off     = (int*)(ws + 23430000);        // 256 (g_off[196] valid)
    unsigned short* Wt1 = (unsigned short*)(ws + 23500000);    // 65,536 shorts
    unsigned short* Wt2 = (unsigned short*)(ws + 23550000);    // 32,768 shorts
    unsigned short* Wt3 = (unsigned short*)(ws + 23600000);    // 4,096 shorts

    // K1: weight prep (400 blocks) + per-block coarse dst histograms (416 blocks)
    k_prep<<<400 + HBLK, 256, 0, stream>>>(W1l, W1r, W2l, W2r, Wlin,
                                           Wt1, Wt2, Wt3, ei, part);
    // K2: gemm1 both flavors (391 blocks) + self-deriving CSR pass A (416 blocks)
    k_g1h<<<391 + HBLK, 256, 0, stream>>>(x, Wt1, XL1b, XR1b, ei, part, g_off, tmp);
    // K3: CSR pass B: per-group counting sort -> csr/rowstart/deg
    k_bsort<<<NGRP, 256, 0, stream>>>(tmp, g_off, rowstart, deg, csr);
    // K4: layer-1 fused attention
    k_node1<<<12500, 256, 0, stream>>>(rowstart, deg, csr,
                                       (const uint4*)XL1b, (const uint4*)XR1b,
                                       att1, b1, H1b);
    // K5: layer-2 projection
    k_gemm2<<<782, 256, 0, stream>>>((const uint4*)H1b, Wt2, XL2b, XR2b);
    // K6: layer-2 fused attention + final linear (gemm3 fused via MFMA)
    k_node2<<<12500, 256, 0, stream>>>(rowstart, deg, csr,
                                       (const uint2*)XL2b, (const uint2*)XR2b,
                                       att2, b2, Wt3, blin, (float*)d_out);
}